// Round 5
// baseline (333.163 us; speedup 1.0000x reference)
//
#include <hip/hip_runtime.h>

typedef __fp16 half2_t __attribute__((ext_vector_type(2)));

#define D 128
#define LN_EPS 1e-5f
#define BUCKET_NODES 128
#define BUCKET_SHIFT 7
#define EDGE_CAP 4096          // avg ~2046 edges/bucket, sigma ~45; 45-sigma headroom
#define FUSE_THREADS 512
#define K2_EPT 32              // 16384 edges per fill block (longer write runs)
#define GT 1024                // gather block threads (16 waves)

// split-f16 packing: word f of a row holds (feat f, feat f+64) as packed f16
__device__ inline unsigned pack_h2(float a, float b) {
    half2_t p = __builtin_amdgcn_cvt_pkrtz(a, b);
    return __builtin_bit_cast(unsigned, p);
}

// ---- K1: stitched conv (x f32 -> xb split-f16, vectorized x4) + bucket fill ----
// conv: 4 words/thread via float4 loads + uint4 store (was 4-B scalar).
// fill: 32 edges/thread; pass1 reads dst only + LDS hist (staging 1 VGPR/edge),
// pass3 re-reads src/val (sequential, L2-hot) -> longer line-dense write runs
// (avg 21 edges = 168 B vs 84 B at EPT=16) without register-spill risk.
__global__ __launch_bounds__(FUSE_THREADS)
void conv_fill_kernel(const float* __restrict__ x, unsigned int* __restrict__ xb,
                      int conv_items, int conv_blocks,
                      const int* __restrict__ src, const int* __restrict__ dst,
                      const float* __restrict__ val,
                      int* __restrict__ gcnt, uint2* __restrict__ edges,
                      int E, int nbuckets) {
    if ((int)blockIdx.x < conv_blocks) {
        int i4 = blockIdx.x * FUSE_THREADS + threadIdx.x;
        if (i4 < conv_items) {
            int node = i4 >> 4, f4 = (i4 & 15) << 2;
            float4 xA = *(const float4*)(x + (size_t)node * D + f4);
            float4 xB = *(const float4*)(x + (size_t)node * D + 64 + f4);
            uint4 pw;
            pw.x = pack_h2(xA.x, xB.x); pw.y = pack_h2(xA.y, xB.y);
            pw.z = pack_h2(xA.z, xB.z); pw.w = pack_h2(xA.w, xB.w);
            *(uint4*)(xb + (size_t)node * 64 + f4) = pw;
        }
        return;
    }
    __shared__ int lcnt[1024];
    __shared__ int lbase[1024];
    int fb = (int)blockIdx.x - conv_blocks;
    for (int i = threadIdx.x; i < nbuckets; i += FUSE_THREADS) lcnt[i] = 0;
    __syncthreads();

    int base = fb * (FUSE_THREADS * K2_EPT);
    // br[r]: [31:21]=bucket (<=1023), [20:14]=dst_local, [13:0]=rank (<16384)
    unsigned int br[K2_EPT];
    #pragma unroll
    for (int r = 0; r < K2_EPT; ++r) {
        int e = base + r * FUSE_THREADS + threadIdx.x;
        if (e < E) {
            int d = dst[e];
            int b = d >> BUCKET_SHIFT;
            int rk = atomicAdd(&lcnt[b], 1);
            br[r] = ((unsigned)b << 21) | ((unsigned)(d & (BUCKET_NODES - 1)) << 14)
                  | (unsigned)rk;
        }
    }
    __syncthreads();
    for (int i = threadIdx.x; i < nbuckets; i += FUSE_THREADS) {
        int c = lcnt[i];
        lbase[i] = c ? atomicAdd(&gcnt[i], c) : 0;
    }
    __syncthreads();
    #pragma unroll
    for (int r = 0; r < K2_EPT; ++r) {
        int e = base + r * FUSE_THREADS + threadIdx.x;
        if (e < E) {
            unsigned u = br[r];
            int b    = (int)(u >> 21);
            int dstl = (int)((u >> 14) & 127u);
            int rk   = (int)(u & 16383u);
            int slot = lbase[b] + rk;
            if (slot < EDGE_CAP)
                edges[(size_t)b * EDGE_CAP + slot] =
                    make_uint2((unsigned)src[e] | ((unsigned)dstl << 20),
                               __float_as_uint(val[e]));
        }
    }
}

// ---- K2: block per bucket: LDS counting-sort + gather + diag-w + LN (+ReLU) ----
// 16-lane group = one node (4 nodes/wave). Lane sl covers feats
// {4sl..4sl+3} u {64+4sl..64+4sl+3} via split-f16 uint4 row loads.
// NOTE (r1-r4 arc): this dispatch obeys dur ~= (FETCH+WRITE)/3.3 TB/s across
// every scheduling variant tried (ILP 4-deep, SWP, sched_barrier) -- it is
// L2-fill bound on random 256-B gathers. Keep the r0 form (best measured).
__global__ __launch_bounds__(GT, 8)
void gather_ln_kernel(const uint4* __restrict__ h4,
                      const int* __restrict__ gcnt,
                      const uint2* __restrict__ edges_g,
                      const float* __restrict__ w,
                      const float* __restrict__ g,
                      const float* __restrict__ bb,
                      float* __restrict__ out_f32,
                      unsigned int* __restrict__ out_h,
                      int N, int mode) {
    __shared__ uint2 eL[EDGE_CAP];          // 32 KB sorted edge list
    __shared__ int hist[BUCKET_NODES];
    __shared__ int scanb[BUCKET_NODES];
    __shared__ int obase[BUCKET_NODES];

    int bkt = blockIdx.x;
    int tid = threadIdx.x;
    int cnt = min(gcnt[bkt], EDGE_CAP);
    const uint2* ep = edges_g + (size_t)bkt * EDGE_CAP;

    if (tid < BUCKET_NODES) hist[tid] = 0;
    __syncthreads();

    uint2 ed[4]; int dl[4]; int rk[4];
    #pragma unroll
    for (int r = 0; r < 4; ++r) {
        int i = r * GT + tid;
        if (i < cnt) {
            uint2 t = ep[i];
            ed[r] = t;
            dl[r] = (int)(t.x >> 20);
            rk[r] = atomicAdd(&hist[dl[r]], 1);
        } else dl[r] = -1;
    }
    __syncthreads();
    if (tid < BUCKET_NODES) scanb[tid] = hist[tid];
    __syncthreads();
    #pragma unroll
    for (int off = 1; off < BUCKET_NODES; off <<= 1) {
        int v = 0;
        if (tid < BUCKET_NODES && tid >= off) v = scanb[tid - off];
        __syncthreads();
        if (tid < BUCKET_NODES) scanb[tid] += v;
        __syncthreads();
    }
    if (tid < BUCKET_NODES) obase[tid] = scanb[tid] - hist[tid];
    __syncthreads();
    #pragma unroll
    for (int r = 0; r < 4; ++r)
        if (dl[r] >= 0) eL[obase[dl[r]] + rk[r]] = ed[r];
    __syncthreads();

    int wid = tid >> 6, lane = tid & 63, grp = lane >> 4, sl = lane & 15;

    float4 wA = ((const float4*)w)[sl];
    float4 wB = ((const float4*)(w + 64))[sl];
    float4 gA = ((const float4*)g)[sl];
    float4 gB = ((const float4*)(g + 64))[sl];
    float4 bA = ((const float4*)bb)[sl];
    float4 bB = ((const float4*)(bb + 64))[sl];

    #pragma unroll
    for (int k = 0; k < 2; ++k) {
        int ni = k * 64 + wid * 4 + grp;            // 0..127
        int n = (bkt << BUCKET_SHIFT) + ni;
        if (n >= N) continue;
        int st = obase[ni], m = hist[ni];

        float aA0=0,aA1=0,aA2=0,aA3=0, aB0=0,aB1=0,aB2=0,aB3=0;
        for (int j = 0; j < m; j += 2) {
            uint2 tA = eL[st + j];                  // group-uniform: LDS broadcast
            uint2 tB = (j + 1 < m) ? eL[st + j + 1] : make_uint2(0u, 0u);
            int   sA = (int)(tA.x & 0xfffffu);
            float vA = __uint_as_float(tA.y);
            int   sB = (int)(tB.x & 0xfffffu);
            float vB = __uint_as_float(tB.y);       // 0 on pad -> no contribution
            uint4 hA = h4[(size_t)sA * 16 + sl];
            uint4 hB = h4[(size_t)sB * 16 + sl];
            half2_t p;
            p = __builtin_bit_cast(half2_t, hA.x);
            aA0 = fmaf(vA, (float)p.x, aA0); aB0 = fmaf(vA, (float)p.y, aB0);
            p = __builtin_bit_cast(half2_t, hA.y);
            aA1 = fmaf(vA, (float)p.x, aA1); aB1 = fmaf(vA, (float)p.y, aB1);
            p = __builtin_bit_cast(half2_t, hA.z);
            aA2 = fmaf(vA, (float)p.x, aA2); aB2 = fmaf(vA, (float)p.y, aB2);
            p = __builtin_bit_cast(half2_t, hA.w);
            aA3 = fmaf(vA, (float)p.x, aA3); aB3 = fmaf(vA, (float)p.y, aB3);
            p = __builtin_bit_cast(half2_t, hB.x);
            aA0 = fmaf(vB, (float)p.x, aA0); aB0 = fmaf(vB, (float)p.y, aB0);
            p = __builtin_bit_cast(half2_t, hB.y);
            aA1 = fmaf(vB, (float)p.x, aA1); aB1 = fmaf(vB, (float)p.y, aB1);
            p = __builtin_bit_cast(half2_t, hB.z);
            aA2 = fmaf(vB, (float)p.x, aA2); aB2 = fmaf(vB, (float)p.y, aB2);
            p = __builtin_bit_cast(half2_t, hB.w);
            aA3 = fmaf(vB, (float)p.x, aA3); aB3 = fmaf(vB, (float)p.y, aB3);
        }

        aA0 *= wA.x; aA1 *= wA.y; aA2 *= wA.z; aA3 *= wA.w;
        aB0 *= wB.x; aB1 *= wB.y; aB2 *= wB.z; aB3 *= wB.w;

        // LN over 128 feats: intra-lane 8 + 4 shfl_xor within the 16-lane group
        float sum = ((aA0 + aA1) + (aA2 + aA3)) + ((aB0 + aB1) + (aB2 + aB3));
        sum += __shfl_xor(sum, 1, 64); sum += __shfl_xor(sum, 2, 64);
        sum += __shfl_xor(sum, 4, 64); sum += __shfl_xor(sum, 8, 64);
        float mu = sum * (1.0f / D);

        float dA0 = aA0 - mu, dA1 = aA1 - mu, dA2 = aA2 - mu, dA3 = aA3 - mu;
        float dB0 = aB0 - mu, dB1 = aB1 - mu, dB2 = aB2 - mu, dB3 = aB3 - mu;
        float sq = ((dA0*dA0 + dA1*dA1) + (dA2*dA2 + dA3*dA3))
                 + ((dB0*dB0 + dB1*dB1) + (dB2*dB2 + dB3*dB3));
        sq += __shfl_xor(sq, 1, 64); sq += __shfl_xor(sq, 2, 64);
        sq += __shfl_xor(sq, 4, 64); sq += __shfl_xor(sq, 8, 64);
        float rstd = rsqrtf(sq * (1.0f / D) + LN_EPS);

        float oA0 = dA0 * rstd * gA.x + bA.x, oA1 = dA1 * rstd * gA.y + bA.y;
        float oA2 = dA2 * rstd * gA.z + bA.z, oA3 = dA3 * rstd * gA.w + bA.w;
        float oB0 = dB0 * rstd * gB.x + bB.x, oB1 = dB1 * rstd * gB.y + bB.y;
        float oB2 = dB2 * rstd * gB.z + bB.z, oB3 = dB3 * rstd * gB.w + bB.w;

        if (mode == 1) {
            oA0 = fmaxf(oA0, 0.f); oA1 = fmaxf(oA1, 0.f);
            oA2 = fmaxf(oA2, 0.f); oA3 = fmaxf(oA3, 0.f);
            oB0 = fmaxf(oB0, 0.f); oB1 = fmaxf(oB1, 0.f);
            oB2 = fmaxf(oB2, 0.f); oB3 = fmaxf(oB3, 0.f);
            uint4 pw;
            pw.x = pack_h2(oA0, oB0); pw.y = pack_h2(oA1, oB1);
            pw.z = pack_h2(oA2, oB2); pw.w = pack_h2(oA3, oB3);
            ((uint4*)(out_h + (size_t)n * 64))[sl] = pw;
        } else {
            ((float4*)(out_f32 + (size_t)n * D))[sl]      = make_float4(oA0, oA1, oA2, oA3);
            ((float4*)(out_f32 + (size_t)n * D + 64))[sl] = make_float4(oB0, oB1, oB2, oB3);
        }
    }
}

extern "C" void kernel_launch(void* const* d_in, const int* in_sizes, int n_in,
                              void* d_out, int out_size, void* d_ws, size_t ws_size,
                              hipStream_t stream) {
    const float* x    = (const float*)d_in[0];
    const int*   esrc = (const int*)d_in[1];
    const int*   edst = (const int*)d_in[2];
    const float* eval_= (const float*)d_in[3];
    const float* w1   = (const float*)d_in[4];
    const float* w2   = (const float*)d_in[5];
    const float* g1   = (const float*)d_in[6];
    const float* b1   = (const float*)d_in[7];
    const float* g2   = (const float*)d_in[8];
    const float* b2   = (const float*)d_in[9];
    float* out = (float*)d_out;

    const int N = in_sizes[0] / D;   // 100000
    const int E = in_sizes[1];       // 1600000
    const int nbuckets = (N + BUCKET_NODES - 1) >> BUCKET_SHIFT;   // 782

    unsigned int* xb    = (unsigned int*)d_ws;                 // 25.6 MB
    unsigned int* hb    = xb + (size_t)N * 64;                 // 25.6 MB
    uint2*        edges = (uint2*)(hb + (size_t)N * 64);       // 25.6 MB
    int*          gcnt  = (int*)(edges + (size_t)nbuckets * EDGE_CAP);

    const int conv_items  = N * 16;   // uint4 words (4 packed words per item)
    const int conv_blocks = (conv_items + FUSE_THREADS - 1) / FUSE_THREADS;
    const int fill_blocks = (E + FUSE_THREADS * K2_EPT - 1) / (FUSE_THREADS * K2_EPT);

    (void)hipMemsetAsync(gcnt, 0, (size_t)nbuckets * sizeof(int), stream);
    conv_fill_kernel<<<conv_blocks + fill_blocks, FUSE_THREADS, 0, stream>>>(
        x, xb, conv_items, conv_blocks, esrc, edst, eval_, gcnt, edges, E, nbuckets);
    // layer 1: sort+gather(xb)*w1 -> LN -> ReLU -> hb (f16 split)
    gather_ln_kernel<<<nbuckets, GT, 0, stream>>>((const uint4*)xb, gcnt, edges,
                                                  w1, g1, b1, nullptr, hb, N, 1);
    // layer 2: sort+gather(hb)*w2 -> LN -> out (f32)
    gather_ln_kernel<<<nbuckets, GT, 0, stream>>>((const uint4*)hb, gcnt, edges,
                                                  w2, g2, b2, out, nullptr, N, 0);
}

// Round 6
// 285.119 us; speedup vs baseline: 1.1685x; 1.1685x over previous
//
#include <hip/hip_runtime.h>

typedef __fp16 half2_t __attribute__((ext_vector_type(2)));

#define D 128
#define LN_EPS 1e-5f
#define BUCKET_NODES 128
#define BUCKET_SHIFT 7
#define EDGE_CAP 4096          // avg ~2046 edges/bucket, sigma ~45; 45-sigma headroom
#define FUSE_THREADS 512
#define K2_EPT 4               // 2048 edges per fill block -> 782 fill blocks (TLP!)
#define GT 1024                // gather block threads (16 waves)

// split-f16 packing: word f of a row holds (feat f, feat f+64) as packed f16
__device__ inline unsigned pack_h2(float a, float b) {
    half2_t p = __builtin_amdgcn_cvt_pkrtz(a, b);
    return __builtin_bit_cast(unsigned, p);
}

// ---- K1: stitched bucket fill + conv (x f32 -> xb split-f16, vectorized x4) ----
// r5 lesson: fill at EPT=32 had only 98 blocks (<0.4/CU) and ran EXPOSED after
// the (now fast) conv -> 97 us at 10% occupancy. Fix: EPT=4 -> 782 fill blocks,
// and fill blocks placed FIRST in the grid so their latency hides under the
// 3125 conv blocks that follow. Conv stays vectorized (float4 in / uint4 out).
__global__ __launch_bounds__(FUSE_THREADS)
void conv_fill_kernel(const float* __restrict__ x, unsigned int* __restrict__ xb,
                      int conv_items, int fill_blocks,
                      const int* __restrict__ src, const int* __restrict__ dst,
                      const float* __restrict__ val,
                      int* __restrict__ gcnt, uint2* __restrict__ edges,
                      int E, int nbuckets) {
    if ((int)blockIdx.x >= fill_blocks) {
        int i4 = ((int)blockIdx.x - fill_blocks) * FUSE_THREADS + threadIdx.x;
        if (i4 < conv_items) {
            int node = i4 >> 4, f4 = (i4 & 15) << 2;
            float4 xA = *(const float4*)(x + (size_t)node * D + f4);
            float4 xB = *(const float4*)(x + (size_t)node * D + 64 + f4);
            uint4 pw;
            pw.x = pack_h2(xA.x, xB.x); pw.y = pack_h2(xA.y, xB.y);
            pw.z = pack_h2(xA.z, xB.z); pw.w = pack_h2(xA.w, xB.w);
            *(uint4*)(xb + (size_t)node * 64 + f4) = pw;
        }
        return;
    }
    // fill: per-block LDS hist -> one reservation atomic per bucket ->
    // per-block contiguous write runs (line-dense-ish at 2048 edges/block)
    __shared__ int lcnt[1024];
    __shared__ int lbase[1024];
    int fb = (int)blockIdx.x;
    for (int i = threadIdx.x; i < nbuckets; i += FUSE_THREADS) lcnt[i] = 0;
    __syncthreads();

    int base = fb * (FUSE_THREADS * K2_EPT);
    unsigned int w0[K2_EPT];
    float        w1[K2_EPT];
    int          br[K2_EPT];   // (bucket<<16)|rank, or -1 (rank < 2048 fits)
    #pragma unroll
    for (int r = 0; r < K2_EPT; ++r) {
        int e = base + r * FUSE_THREADS + threadIdx.x;
        if (e < E) {
            int d = dst[e];
            int b = d >> BUCKET_SHIFT;
            int rk = atomicAdd(&lcnt[b], 1);
            w0[r] = (unsigned)src[e] | ((unsigned)(d & (BUCKET_NODES - 1)) << 20);
            w1[r] = val[e];
            br[r] = (b << 16) | rk;
        } else {
            br[r] = -1;
        }
    }
    __syncthreads();
    for (int i = threadIdx.x; i < nbuckets; i += FUSE_THREADS) {
        int c = lcnt[i];
        lbase[i] = c ? atomicAdd(&gcnt[i], c) : 0;
    }
    __syncthreads();
    #pragma unroll
    for (int r = 0; r < K2_EPT; ++r) {
        if (br[r] >= 0) {
            int b    = br[r] >> 16;
            int rk   = br[r] & 0xffff;
            int slot = lbase[b] + rk;
            if (slot < EDGE_CAP)
                edges[(size_t)b * EDGE_CAP + slot] =
                    make_uint2(w0[r], __float_as_uint(w1[r]));
        }
    }
}

// ---- K2: block per bucket: LDS counting-sort + gather + diag-w + LN (+ReLU) ----
// 16-lane group = one node (4 nodes/wave). Lane sl covers feats
// {4sl..4sl+3} u {64+4sl..64+4sl+3} via split-f16 uint4 row loads.
// NOTE (r1-r4 arc): this dispatch obeys dur ~= (FETCH+WRITE)/3.3 TB/s across
// every scheduling variant tried (ILP 4-deep, SWP, sched_barrier) -- it is
// L2-fill bound on random 256-B gathers. Keep the r0 form (best measured).
__global__ __launch_bounds__(GT, 8)
void gather_ln_kernel(const uint4* __restrict__ h4,
                      const int* __restrict__ gcnt,
                      const uint2* __restrict__ edges_g,
                      const float* __restrict__ w,
                      const float* __restrict__ g,
                      const float* __restrict__ bb,
                      float* __restrict__ out_f32,
                      unsigned int* __restrict__ out_h,
                      int N, int mode) {
    __shared__ uint2 eL[EDGE_CAP];          // 32 KB sorted edge list
    __shared__ int hist[BUCKET_NODES];
    __shared__ int scanb[BUCKET_NODES];
    __shared__ int obase[BUCKET_NODES];

    int bkt = blockIdx.x;
    int tid = threadIdx.x;
    int cnt = min(gcnt[bkt], EDGE_CAP);
    const uint2* ep = edges_g + (size_t)bkt * EDGE_CAP;

    if (tid < BUCKET_NODES) hist[tid] = 0;
    __syncthreads();

    uint2 ed[4]; int dl[4]; int rk[4];
    #pragma unroll
    for (int r = 0; r < 4; ++r) {
        int i = r * GT + tid;
        if (i < cnt) {
            uint2 t = ep[i];
            ed[r] = t;
            dl[r] = (int)(t.x >> 20);
            rk[r] = atomicAdd(&hist[dl[r]], 1);
        } else dl[r] = -1;
    }
    __syncthreads();
    if (tid < BUCKET_NODES) scanb[tid] = hist[tid];
    __syncthreads();
    #pragma unroll
    for (int off = 1; off < BUCKET_NODES; off <<= 1) {
        int v = 0;
        if (tid < BUCKET_NODES && tid >= off) v = scanb[tid - off];
        __syncthreads();
        if (tid < BUCKET_NODES) scanb[tid] += v;
        __syncthreads();
    }
    if (tid < BUCKET_NODES) obase[tid] = scanb[tid] - hist[tid];
    __syncthreads();
    #pragma unroll
    for (int r = 0; r < 4; ++r)
        if (dl[r] >= 0) eL[obase[dl[r]] + rk[r]] = ed[r];
    __syncthreads();

    int wid = tid >> 6, lane = tid & 63, grp = lane >> 4, sl = lane & 15;

    float4 wA = ((const float4*)w)[sl];
    float4 wB = ((const float4*)(w + 64))[sl];
    float4 gA = ((const float4*)g)[sl];
    float4 gB = ((const float4*)(g + 64))[sl];
    float4 bA = ((const float4*)bb)[sl];
    float4 bB = ((const float4*)(bb + 64))[sl];

    #pragma unroll
    for (int k = 0; k < 2; ++k) {
        int ni = k * 64 + wid * 4 + grp;            // 0..127
        int n = (bkt << BUCKET_SHIFT) + ni;
        if (n >= N) continue;
        int st = obase[ni], m = hist[ni];

        float aA0=0,aA1=0,aA2=0,aA3=0, aB0=0,aB1=0,aB2=0,aB3=0;
        for (int j = 0; j < m; j += 2) {
            uint2 tA = eL[st + j];                  // group-uniform: LDS broadcast
            uint2 tB = (j + 1 < m) ? eL[st + j + 1] : make_uint2(0u, 0u);
            int   sA = (int)(tA.x & 0xfffffu);
            float vA = __uint_as_float(tA.y);
            int   sB = (int)(tB.x & 0xfffffu);
            float vB = __uint_as_float(tB.y);       // 0 on pad -> no contribution
            uint4 hA = h4[(size_t)sA * 16 + sl];
            uint4 hB = h4[(size_t)sB * 16 + sl];
            half2_t p;
            p = __builtin_bit_cast(half2_t, hA.x);
            aA0 = fmaf(vA, (float)p.x, aA0); aB0 = fmaf(vA, (float)p.y, aB0);
            p = __builtin_bit_cast(half2_t, hA.y);
            aA1 = fmaf(vA, (float)p.x, aA1); aB1 = fmaf(vA, (float)p.y, aB1);
            p = __builtin_bit_cast(half2_t, hA.z);
            aA2 = fmaf(vA, (float)p.x, aA2); aB2 = fmaf(vA, (float)p.y, aB2);
            p = __builtin_bit_cast(half2_t, hA.w);
            aA3 = fmaf(vA, (float)p.x, aA3); aB3 = fmaf(vA, (float)p.y, aB3);
            p = __builtin_bit_cast(half2_t, hB.x);
            aA0 = fmaf(vB, (float)p.x, aA0); aB0 = fmaf(vB, (float)p.y, aB0);
            p = __builtin_bit_cast(half2_t, hB.y);
            aA1 = fmaf(vB, (float)p.x, aA1); aB1 = fmaf(vB, (float)p.y, aB1);
            p = __builtin_bit_cast(half2_t, hB.z);
            aA2 = fmaf(vB, (float)p.x, aA2); aB2 = fmaf(vB, (float)p.y, aB2);
            p = __builtin_bit_cast(half2_t, hB.w);
            aA3 = fmaf(vB, (float)p.x, aA3); aB3 = fmaf(vB, (float)p.y, aB3);
        }

        aA0 *= wA.x; aA1 *= wA.y; aA2 *= wA.z; aA3 *= wA.w;
        aB0 *= wB.x; aB1 *= wB.y; aB2 *= wB.z; aB3 *= wB.w;

        // LN over 128 feats: intra-lane 8 + 4 shfl_xor within the 16-lane group
        float sum = ((aA0 + aA1) + (aA2 + aA3)) + ((aB0 + aB1) + (aB2 + aB3));
        sum += __shfl_xor(sum, 1, 64); sum += __shfl_xor(sum, 2, 64);
        sum += __shfl_xor(sum, 4, 64); sum += __shfl_xor(sum, 8, 64);
        float mu = sum * (1.0f / D);

        float dA0 = aA0 - mu, dA1 = aA1 - mu, dA2 = aA2 - mu, dA3 = aA3 - mu;
        float dB0 = aB0 - mu, dB1 = aB1 - mu, dB2 = aB2 - mu, dB3 = aB3 - mu;
        float sq = ((dA0*dA0 + dA1*dA1) + (dA2*dA2 + dA3*dA3))
                 + ((dB0*dB0 + dB1*dB1) + (dB2*dB2 + dB3*dB3));
        sq += __shfl_xor(sq, 1, 64); sq += __shfl_xor(sq, 2, 64);
        sq += __shfl_xor(sq, 4, 64); sq += __shfl_xor(sq, 8, 64);
        float rstd = rsqrtf(sq * (1.0f / D) + LN_EPS);

        float oA0 = dA0 * rstd * gA.x + bA.x, oA1 = dA1 * rstd * gA.y + bA.y;
        float oA2 = dA2 * rstd * gA.z + bA.z, oA3 = dA3 * rstd * gA.w + bA.w;
        float oB0 = dB0 * rstd * gB.x + bB.x, oB1 = dB1 * rstd * gB.y + bB.y;
        float oB2 = dB2 * rstd * gB.z + bB.z, oB3 = dB3 * rstd * gB.w + bB.w;

        if (mode == 1) {
            oA0 = fmaxf(oA0, 0.f); oA1 = fmaxf(oA1, 0.f);
            oA2 = fmaxf(oA2, 0.f); oA3 = fmaxf(oA3, 0.f);
            oB0 = fmaxf(oB0, 0.f); oB1 = fmaxf(oB1, 0.f);
            oB2 = fmaxf(oB2, 0.f); oB3 = fmaxf(oB3, 0.f);
            uint4 pw;
            pw.x = pack_h2(oA0, oB0); pw.y = pack_h2(oA1, oB1);
            pw.z = pack_h2(oA2, oB2); pw.w = pack_h2(oA3, oB3);
            ((uint4*)(out_h + (size_t)n * 64))[sl] = pw;
        } else {
            ((float4*)(out_f32 + (size_t)n * D))[sl]      = make_float4(oA0, oA1, oA2, oA3);
            ((float4*)(out_f32 + (size_t)n * D + 64))[sl] = make_float4(oB0, oB1, oB2, oB3);
        }
    }
}

extern "C" void kernel_launch(void* const* d_in, const int* in_sizes, int n_in,
                              void* d_out, int out_size, void* d_ws, size_t ws_size,
                              hipStream_t stream) {
    const float* x    = (const float*)d_in[0];
    const int*   esrc = (const int*)d_in[1];
    const int*   edst = (const int*)d_in[2];
    const float* eval_= (const float*)d_in[3];
    const float* w1   = (const float*)d_in[4];
    const float* w2   = (const float*)d_in[5];
    const float* g1   = (const float*)d_in[6];
    const float* b1   = (const float*)d_in[7];
    const float* g2   = (const float*)d_in[8];
    const float* b2   = (const float*)d_in[9];
    float* out = (float*)d_out;

    const int N = in_sizes[0] / D;   // 100000
    const int E = in_sizes[1];       // 1600000
    const int nbuckets = (N + BUCKET_NODES - 1) >> BUCKET_SHIFT;   // 782

    unsigned int* xb    = (unsigned int*)d_ws;                 // 25.6 MB
    unsigned int* hb    = xb + (size_t)N * 64;                 // 25.6 MB
    uint2*        edges = (uint2*)(hb + (size_t)N * 64);       // 25.6 MB
    int*          gcnt  = (int*)(edges + (size_t)nbuckets * EDGE_CAP);

    const int conv_items  = N * 16;   // uint4 items (4 packed words per item)
    const int conv_blocks = (conv_items + FUSE_THREADS - 1) / FUSE_THREADS;
    const int fill_blocks = (E + FUSE_THREADS * K2_EPT - 1) / (FUSE_THREADS * K2_EPT);

    (void)hipMemsetAsync(gcnt, 0, (size_t)nbuckets * sizeof(int), stream);
    // fill blocks FIRST: their latency hides under the conv blocks behind them
    conv_fill_kernel<<<fill_blocks + conv_blocks, FUSE_THREADS, 0, stream>>>(
        x, xb, conv_items, fill_blocks, esrc, edst, eval_, gcnt, edges, E, nbuckets);
    // layer 1: sort+gather(xb)*w1 -> LN -> ReLU -> hb (f16 split)
    gather_ln_kernel<<<nbuckets, GT, 0, stream>>>((const uint4*)xb, gcnt, edges,
                                                  w1, g1, b1, nullptr, hb, N, 1);
    // layer 2: sort+gather(hb)*w2 -> LN -> out (f32)
    gather_ln_kernel<<<nbuckets, GT, 0, stream>>>((const uint4*)hb, gcnt, edges,
                                                  w2, g2, b2, out, nullptr, N, 0);
}

// Round 7
// 271.244 us; speedup vs baseline: 1.2283x; 1.0512x over previous
//
#include <hip/hip_runtime.h>

typedef __fp16 half2_t __attribute__((ext_vector_type(2)));

#define D 128
#define LN_EPS 1e-5f
#define BUCKET_NODES 128
#define BUCKET_SHIFT 7
#define EDGE_CAP 4096          // avg ~2046 edges/bucket, sigma ~45; 45-sigma headroom
#define FUSE_THREADS 512
#define K2_EPT 8               // 4096 edges per fill block -> 391 fill blocks
                               // (r5: EPT=32/98 blocks latency-exposed; r6: EPT=4
                               //  runs only 2.6 edges=21B -> sector waste. EPT=8:
                               //  5.2-edge=42B runs, still 1.5 blocks/CU TLP)
#define GT 1024                // gather block threads (16 waves)

// split-f16 packing: word f of a row holds (feat f, feat f+64) as packed f16
__device__ inline unsigned pack_h2(float a, float b) {
    half2_t p = __builtin_amdgcn_cvt_pkrtz(a, b);
    return __builtin_bit_cast(unsigned, p);
}

// ---- K1: stitched bucket fill + conv (x f32 -> xb split-f16, vectorized x4) ----
// fill blocks FIRST: they start immediately and their latency hides under the
// 3125 vectorized conv blocks dispatched behind them (r6 lesson).
__global__ __launch_bounds__(FUSE_THREADS)
void conv_fill_kernel(const float* __restrict__ x, unsigned int* __restrict__ xb,
                      int conv_items, int fill_blocks,
                      const int* __restrict__ src, const int* __restrict__ dst,
                      const float* __restrict__ val,
                      int* __restrict__ gcnt, uint2* __restrict__ edges,
                      int E, int nbuckets) {
    if ((int)blockIdx.x >= fill_blocks) {
        int i4 = ((int)blockIdx.x - fill_blocks) * FUSE_THREADS + threadIdx.x;
        if (i4 < conv_items) {
            int node = i4 >> 4, f4 = (i4 & 15) << 2;
            float4 xA = *(const float4*)(x + (size_t)node * D + f4);
            float4 xB = *(const float4*)(x + (size_t)node * D + 64 + f4);
            uint4 pw;
            pw.x = pack_h2(xA.x, xB.x); pw.y = pack_h2(xA.y, xB.y);
            pw.z = pack_h2(xA.z, xB.z); pw.w = pack_h2(xA.w, xB.w);
            *(uint4*)(xb + (size_t)node * 64 + f4) = pw;
        }
        return;
    }
    // fill: per-block LDS hist -> one reservation atomic per bucket ->
    // per-block contiguous write runs (avg 5.2 edges = 42 B at EPT=8)
    __shared__ int lcnt[1024];
    __shared__ int lbase[1024];
    int fb = (int)blockIdx.x;
    for (int i = threadIdx.x; i < nbuckets; i += FUSE_THREADS) lcnt[i] = 0;
    __syncthreads();

    int base = fb * (FUSE_THREADS * K2_EPT);
    unsigned int w0[K2_EPT];
    float        w1[K2_EPT];
    int          br[K2_EPT];   // (bucket<<16)|rank, or -1 (rank < 4096 fits 16b)
    #pragma unroll
    for (int r = 0; r < K2_EPT; ++r) {
        int e = base + r * FUSE_THREADS + threadIdx.x;
        if (e < E) {
            int d = dst[e];
            int b = d >> BUCKET_SHIFT;
            int rk = atomicAdd(&lcnt[b], 1);
            w0[r] = (unsigned)src[e] | ((unsigned)(d & (BUCKET_NODES - 1)) << 20);
            w1[r] = val[e];
            br[r] = (b << 16) | rk;
        } else {
            br[r] = -1;
        }
    }
    __syncthreads();
    for (int i = threadIdx.x; i < nbuckets; i += FUSE_THREADS) {
        int c = lcnt[i];
        lbase[i] = c ? atomicAdd(&gcnt[i], c) : 0;
    }
    __syncthreads();
    #pragma unroll
    for (int r = 0; r < K2_EPT; ++r) {
        if (br[r] >= 0) {
            int b    = br[r] >> 16;
            int rk   = br[r] & 0xffff;
            int slot = lbase[b] + rk;
            if (slot < EDGE_CAP)
                edges[(size_t)b * EDGE_CAP + slot] =
                    make_uint2(w0[r], __float_as_uint(w1[r]));
        }
    }
}

// ---- K2: block per bucket: LDS counting-sort + gather + diag-w + LN (+ReLU) ----
// 16-lane group = one node (4 nodes/wave). Lane sl covers feats
// {4sl..4sl+3} u {64+4sl..64+4sl+3} via split-f16 uint4 row loads.
// NOTE (r1-r4 arc): this dispatch obeys dur ~= (FETCH+WRITE)/3.3 TB/s across
// every scheduling variant tried (ILP 4-deep, SWP, sched_barrier) -- it is
// bound on beyond-L2 random-fabric bandwidth. DO NOT TOUCH (r0 form, best).
__global__ __launch_bounds__(GT, 8)
void gather_ln_kernel(const uint4* __restrict__ h4,
                      const int* __restrict__ gcnt,
                      const uint2* __restrict__ edges_g,
                      const float* __restrict__ w,
                      const float* __restrict__ g,
                      const float* __restrict__ bb,
                      float* __restrict__ out_f32,
                      unsigned int* __restrict__ out_h,
                      int N, int mode) {
    __shared__ uint2 eL[EDGE_CAP];          // 32 KB sorted edge list
    __shared__ int hist[BUCKET_NODES];
    __shared__ int scanb[BUCKET_NODES];
    __shared__ int obase[BUCKET_NODES];

    int bkt = blockIdx.x;
    int tid = threadIdx.x;
    int cnt = min(gcnt[bkt], EDGE_CAP);
    const uint2* ep = edges_g + (size_t)bkt * EDGE_CAP;

    if (tid < BUCKET_NODES) hist[tid] = 0;
    __syncthreads();

    uint2 ed[4]; int dl[4]; int rk[4];
    #pragma unroll
    for (int r = 0; r < 4; ++r) {
        int i = r * GT + tid;
        if (i < cnt) {
            uint2 t = ep[i];
            ed[r] = t;
            dl[r] = (int)(t.x >> 20);
            rk[r] = atomicAdd(&hist[dl[r]], 1);
        } else dl[r] = -1;
    }
    __syncthreads();
    if (tid < BUCKET_NODES) scanb[tid] = hist[tid];
    __syncthreads();
    #pragma unroll
    for (int off = 1; off < BUCKET_NODES; off <<= 1) {
        int v = 0;
        if (tid < BUCKET_NODES && tid >= off) v = scanb[tid - off];
        __syncthreads();
        if (tid < BUCKET_NODES) scanb[tid] += v;
        __syncthreads();
    }
    if (tid < BUCKET_NODES) obase[tid] = scanb[tid] - hist[tid];
    __syncthreads();
    #pragma unroll
    for (int r = 0; r < 4; ++r)
        if (dl[r] >= 0) eL[obase[dl[r]] + rk[r]] = ed[r];
    __syncthreads();

    int wid = tid >> 6, lane = tid & 63, grp = lane >> 4, sl = lane & 15;

    float4 wA = ((const float4*)w)[sl];
    float4 wB = ((const float4*)(w + 64))[sl];
    float4 gA = ((const float4*)g)[sl];
    float4 gB = ((const float4*)(g + 64))[sl];
    float4 bA = ((const float4*)bb)[sl];
    float4 bB = ((const float4*)(bb + 64))[sl];

    #pragma unroll
    for (int k = 0; k < 2; ++k) {
        int ni = k * 64 + wid * 4 + grp;            // 0..127
        int n = (bkt << BUCKET_SHIFT) + ni;
        if (n >= N) continue;
        int st = obase[ni], m = hist[ni];

        float aA0=0,aA1=0,aA2=0,aA3=0, aB0=0,aB1=0,aB2=0,aB3=0;
        for (int j = 0; j < m; j += 2) {
            uint2 tA = eL[st + j];                  // group-uniform: LDS broadcast
            uint2 tB = (j + 1 < m) ? eL[st + j + 1] : make_uint2(0u, 0u);
            int   sA = (int)(tA.x & 0xfffffu);
            float vA = __uint_as_float(tA.y);
            int   sB = (int)(tB.x & 0xfffffu);
            float vB = __uint_as_float(tB.y);       // 0 on pad -> no contribution
            uint4 hA = h4[(size_t)sA * 16 + sl];
            uint4 hB = h4[(size_t)sB * 16 + sl];
            half2_t p;
            p = __builtin_bit_cast(half2_t, hA.x);
            aA0 = fmaf(vA, (float)p.x, aA0); aB0 = fmaf(vA, (float)p.y, aB0);
            p = __builtin_bit_cast(half2_t, hA.y);
            aA1 = fmaf(vA, (float)p.x, aA1); aB1 = fmaf(vA, (float)p.y, aB1);
            p = __builtin_bit_cast(half2_t, hA.z);
            aA2 = fmaf(vA, (float)p.x, aA2); aB2 = fmaf(vA, (float)p.y, aB2);
            p = __builtin_bit_cast(half2_t, hA.w);
            aA3 = fmaf(vA, (float)p.x, aA3); aB3 = fmaf(vA, (float)p.y, aB3);
            p = __builtin_bit_cast(half2_t, hB.x);
            aA0 = fmaf(vB, (float)p.x, aA0); aB0 = fmaf(vB, (float)p.y, aB0);
            p = __builtin_bit_cast(half2_t, hB.y);
            aA1 = fmaf(vB, (float)p.x, aA1); aB1 = fmaf(vB, (float)p.y, aB1);
            p = __builtin_bit_cast(half2_t, hB.z);
            aA2 = fmaf(vB, (float)p.x, aA2); aB2 = fmaf(vB, (float)p.y, aB2);
            p = __builtin_bit_cast(half2_t, hB.w);
            aA3 = fmaf(vB, (float)p.x, aA3); aB3 = fmaf(vB, (float)p.y, aB3);
        }

        aA0 *= wA.x; aA1 *= wA.y; aA2 *= wA.z; aA3 *= wA.w;
        aB0 *= wB.x; aB1 *= wB.y; aB2 *= wB.z; aB3 *= wB.w;

        // LN over 128 feats: intra-lane 8 + 4 shfl_xor within the 16-lane group
        float sum = ((aA0 + aA1) + (aA2 + aA3)) + ((aB0 + aB1) + (aB2 + aB3));
        sum += __shfl_xor(sum, 1, 64); sum += __shfl_xor(sum, 2, 64);
        sum += __shfl_xor(sum, 4, 64); sum += __shfl_xor(sum, 8, 64);
        float mu = sum * (1.0f / D);

        float dA0 = aA0 - mu, dA1 = aA1 - mu, dA2 = aA2 - mu, dA3 = aA3 - mu;
        float dB0 = aB0 - mu, dB1 = aB1 - mu, dB2 = aB2 - mu, dB3 = aB3 - mu;
        float sq = ((dA0*dA0 + dA1*dA1) + (dA2*dA2 + dA3*dA3))
                 + ((dB0*dB0 + dB1*dB1) + (dB2*dB2 + dB3*dB3));
        sq += __shfl_xor(sq, 1, 64); sq += __shfl_xor(sq, 2, 64);
        sq += __shfl_xor(sq, 4, 64); sq += __shfl_xor(sq, 8, 64);
        float rstd = rsqrtf(sq * (1.0f / D) + LN_EPS);

        float oA0 = dA0 * rstd * gA.x + bA.x, oA1 = dA1 * rstd * gA.y + bA.y;
        float oA2 = dA2 * rstd * gA.z + bA.z, oA3 = dA3 * rstd * gA.w + bA.w;
        float oB0 = dB0 * rstd * gB.x + bB.x, oB1 = dB1 * rstd * gB.y + bB.y;
        float oB2 = dB2 * rstd * gB.z + bB.z, oB3 = dB3 * rstd * gB.w + bB.w;

        if (mode == 1) {
            oA0 = fmaxf(oA0, 0.f); oA1 = fmaxf(oA1, 0.f);
            oA2 = fmaxf(oA2, 0.f); oA3 = fmaxf(oA3, 0.f);
            oB0 = fmaxf(oB0, 0.f); oB1 = fmaxf(oB1, 0.f);
            oB2 = fmaxf(oB2, 0.f); oB3 = fmaxf(oB3, 0.f);
            uint4 pw;
            pw.x = pack_h2(oA0, oB0); pw.y = pack_h2(oA1, oB1);
            pw.z = pack_h2(oA2, oB2); pw.w = pack_h2(oA3, oB3);
            ((uint4*)(out_h + (size_t)n * 64))[sl] = pw;
        } else {
            ((float4*)(out_f32 + (size_t)n * D))[sl]      = make_float4(oA0, oA1, oA2, oA3);
            ((float4*)(out_f32 + (size_t)n * D + 64))[sl] = make_float4(oB0, oB1, oB2, oB3);
        }
    }
}

extern "C" void kernel_launch(void* const* d_in, const int* in_sizes, int n_in,
                              void* d_out, int out_size, void* d_ws, size_t ws_size,
                              hipStream_t stream) {
    const float* x    = (const float*)d_in[0];
    const int*   esrc = (const int*)d_in[1];
    const int*   edst = (const int*)d_in[2];
    const float* eval_= (const float*)d_in[3];
    const float* w1   = (const float*)d_in[4];
    const float* w2   = (const float*)d_in[5];
    const float* g1   = (const float*)d_in[6];
    const float* b1   = (const float*)d_in[7];
    const float* g2   = (const float*)d_in[8];
    const float* b2   = (const float*)d_in[9];
    float* out = (float*)d_out;

    const int N = in_sizes[0] / D;   // 100000
    const int E = in_sizes[1];       // 1600000
    const int nbuckets = (N + BUCKET_NODES - 1) >> BUCKET_SHIFT;   // 782

    unsigned int* xb    = (unsigned int*)d_ws;                 // 25.6 MB
    unsigned int* hb    = xb + (size_t)N * 64;                 // 25.6 MB
    uint2*        edges = (uint2*)(hb + (size_t)N * 64);       // 25.6 MB
    int*          gcnt  = (int*)(edges + (size_t)nbuckets * EDGE_CAP);

    const int conv_items  = N * 16;   // uint4 items (4 packed words per item)
    const int conv_blocks = (conv_items + FUSE_THREADS - 1) / FUSE_THREADS;
    const int fill_blocks = (E + FUSE_THREADS * K2_EPT - 1) / (FUSE_THREADS * K2_EPT);

    (void)hipMemsetAsync(gcnt, 0, (size_t)nbuckets * sizeof(int), stream);
    // fill blocks FIRST: their latency hides under the conv blocks behind them
    conv_fill_kernel<<<fill_blocks + conv_blocks, FUSE_THREADS, 0, stream>>>(
        x, xb, conv_items, fill_blocks, esrc, edst, eval_, gcnt, edges, E, nbuckets);
    // layer 1: sort+gather(xb)*w1 -> LN -> ReLU -> hb (f16 split)
    gather_ln_kernel<<<nbuckets, GT, 0, stream>>>((const uint4*)xb, gcnt, edges,
                                                  w1, g1, b1, nullptr, hb, N, 1);
    // layer 2: sort+gather(hb)*w2 -> LN -> out (f32)
    gather_ln_kernel<<<nbuckets, GT, 0, stream>>>((const uint4*)hb, gcnt, edges,
                                                  w2, g2, b2, out, nullptr, N, 0);
}